// Round 5
// baseline (303.854 us; speedup 1.0000x reference)
//
#include <hip/hip_runtime.h>

typedef float f32x2 __attribute__((ext_vector_type(2)));

__device__ __forceinline__ f32x2 splat2(float s) { f32x2 v; v.x = s; v.y = s; return v; }
__device__ __forceinline__ f32x2 pfmas(float a, f32x2 b, f32x2 c) { return __builtin_elementwise_fma(splat2(a), b, c); }
__device__ __forceinline__ f32x2 prelu(f32x2 a) { return __builtin_elementwise_max(a, splat2(0.0f)); }

// ---- ws layout (floats) ----
// [o*24 + 0..5]   j-MLP symmetric weights (cols 0,4,6, (1+2)/2, (3+5)/2, (7+8)/2)
// [o*24 + 6..8]   j-MLP antisymmetric ((1-2)/2, (3-5)/2, (7-8)/2)
// [o*24 + 9]      b1j
// [o*24 +10..18]  n-MLP sym/anti, [o*24+19] b1n
// [o*24 +20] w2j  [o*24+21] w2n   (o = 0..23)
// [576 + r*9 + i] TM[r][i]  (T∘M: tv = TM @ f)
// [672 + r*6 + c] -Minv[r][3+c]   (negated)
// [728] b2j  [729] b2n

__global__ __launch_bounds__(256) void prep_kernel(
    const float* __restrict__ j_w1, const float* __restrict__ j_b1,
    const float* __restrict__ j_w2, const float* __restrict__ j_b2,
    const float* __restrict__ n_w1, const float* __restrict__ n_b1,
    const float* __restrict__ n_w2, const float* __restrict__ n_b2,
    const float* __restrict__ Mg, const float* __restrict__ Minvg,
    float* __restrict__ ws)
{
    const int t = threadIdx.x;
    if (t < 48) {
        const int o = t >> 1, which = t & 1;
        const float* w1 = which ? n_w1 : j_w1;
        const float* b1 = which ? n_b1 : j_b1;
        float w[9];
        #pragma unroll
        for (int i = 0; i < 9; ++i) w[i] = w1[o * 9 + i];
        float* dst = ws + o * 24 + which * 10;
        dst[0] = w[0]; dst[1] = w[4]; dst[2] = w[6];
        dst[3] = 0.5f * (w[1] + w[2]); dst[4] = 0.5f * (w[3] + w[5]); dst[5] = 0.5f * (w[7] + w[8]);
        dst[6] = 0.5f * (w[1] - w[2]); dst[7] = 0.5f * (w[3] - w[5]); dst[8] = 0.5f * (w[7] - w[8]);
        dst[9] = b1[o];
        if (!which) {
            ws[o * 24 + 20] = j_w2[o];
            ws[o * 24 + 21] = n_w2[o];
            ws[o * 24 + 22] = 0.0f;
            ws[o * 24 + 23] = 0.0f;
        }
    } else if (t >= 64 && t < 64 + 81) {
        const int e = t - 64, r = e / 9, i = e % 9;
        float v;
        switch (r) {
            case 0: v = Mg[0 * 9 + i]; break;
            case 1: v = Mg[4 * 9 + i]; break;
            case 2: v = Mg[6 * 9 + i]; break;
            case 3: v = Mg[1 * 9 + i] + Mg[2 * 9 + i]; break;
            case 4: v = Mg[3 * 9 + i] + Mg[5 * 9 + i]; break;
            case 5: v = Mg[7 * 9 + i] + Mg[8 * 9 + i]; break;
            case 6: v = Mg[1 * 9 + i] - Mg[2 * 9 + i]; break;
            case 7: v = Mg[3 * 9 + i] - Mg[5 * 9 + i]; break;
            default: v = Mg[7 * 9 + i] - Mg[8 * 9 + i]; break;
        }
        ws[576 + r * 9 + i] = v;
    } else if (t >= 160 && t < 160 + 54) {
        const int e = t - 160, r = e / 6, c = e % 6;
        ws[672 + e] = -Minvg[r * 9 + 3 + c];
    } else if (t == 254) {
        ws[728] = j_b2[0];
    } else if (t == 255) {
        ws[729] = n_b2[0];
    }
}

__global__ __launch_bounds__(256) void mrt_main(
    const float* __restrict__ f, const float* __restrict__ W,
    float* __restrict__ out, int n2)
{
    // fully uniform control flow: clamp instead of branching
    long base = ((long)blockIdx.x * 256 + threadIdx.x) * 4;
    if (base + 4 > n2) base = n2 - 4;   // same for all shapes; no-op for exact grids

    // ---- load f, accumulate tv = TM @ f (keep f live for the output phase) ----
    f32x2 fv[2][9];
    f32x2 tv[2][9];
    #pragma unroll
    for (int i = 0; i < 9; ++i) {
        const float4 v = *reinterpret_cast<const float4*>(f + (size_t)i * n2 + base);
        fv[0][i].x = v.x; fv[0][i].y = v.y;
        fv[1][i].x = v.z; fv[1][i].y = v.w;
    }
    #pragma unroll
    for (int r = 0; r < 9; ++r) { tv[0][r] = splat2(0.f); tv[1][r] = splat2(0.f); }
    #pragma unroll
    for (int i = 0; i < 9; ++i) {
        #pragma unroll
        for (int r = 0; r < 9; ++r) {
            const float w = W[576 + r * 9 + i];   // uniform -> s_load
            tv[0][r] = pfmas(w, fv[0][i], tv[0][r]);
            tv[1][r] = pfmas(w, fv[1][i], tv[1][r]);
        }
    }

    // ---- fused hidden layer: j(mt), j(mtf), n(mt)+n(mtf) ----
    f32x2 accj[2], accjf[2], accn[2];
    #pragma unroll
    for (int p = 0; p < 2; ++p) { accj[p] = splat2(0.f); accjf[p] = splat2(0.f); accn[p] = splat2(0.f); }

    #pragma unroll 4
    for (int o = 0; o < 24; ++o) {
        const float* wo = W + o * 24;             // uniform base
        const float w0 = wo[0], w1 = wo[1], w2 = wo[2], w3 = wo[3], w4 = wo[4], w5 = wo[5];
        const float a0 = wo[6], a1 = wo[7], a2 = wo[8], b1j = wo[9];
        const float u0 = wo[10], u1 = wo[11], u2 = wo[12], u3 = wo[13], u4 = wo[14], u5 = wo[15];
        const float v0 = wo[16], v1 = wo[17], v2 = wo[18], b1n = wo[19];
        const float w2j = wo[20], w2n = wo[21];
        #pragma unroll
        for (int p = 0; p < 2; ++p) {
            f32x2 s = splat2(b1j);
            s = pfmas(w0, tv[p][0], s);
            s = pfmas(w1, tv[p][1], s);
            s = pfmas(w2, tv[p][2], s);
            s = pfmas(w3, tv[p][3], s);
            s = pfmas(w4, tv[p][4], s);
            s = pfmas(w5, tv[p][5], s);
            f32x2 a = splat2(a0) * tv[p][6];
            a = pfmas(a1, tv[p][7], a);
            a = pfmas(a2, tv[p][8], a);
            accj[p]  = pfmas(w2j, prelu(s + a), accj[p]);
            accjf[p] = pfmas(w2j, prelu(s - a), accjf[p]);

            f32x2 sn = splat2(b1n);
            sn = pfmas(u0, tv[p][0], sn);
            sn = pfmas(u1, tv[p][1], sn);
            sn = pfmas(u2, tv[p][2], sn);
            sn = pfmas(u3, tv[p][3], sn);
            sn = pfmas(u4, tv[p][4], sn);
            sn = pfmas(u5, tv[p][5], sn);
            f32x2 an = splat2(v0) * tv[p][6];
            an = pfmas(v1, tv[p][7], an);
            an = pfmas(v2, tv[p][8], an);
            accn[p] = pfmas(w2n, prelu(sn + an) + prelu(sn - an), accn[p]);
        }
    }

    // ---- taus + Delta = (m - meq)/tau for comps 3..8 ----
    const float b2j = W[728], b2n = W[729];
    f32x2 d[2][6];
    #pragma unroll
    for (int p = 0; p < 2; ++p) {
        const f32x2 aj  = accj[p]  + splat2(b2j);
        const f32x2 ajf = accjf[p] + splat2(b2j);
        const f32x2 an  = accn[p]  + splat2(2.0f * b2n);
        f32x2 rt7, rt8, rt6, rrho;
        rt7.x = __builtin_amdgcn_rcpf(0.5f + __expf(aj.x));
        rt7.y = __builtin_amdgcn_rcpf(0.5f + __expf(aj.y));
        rt8.x = __builtin_amdgcn_rcpf(0.5f + __expf(ajf.x));
        rt8.y = __builtin_amdgcn_rcpf(0.5f + __expf(ajf.y));
        rt6.x = __builtin_amdgcn_rcpf(0.5f + __expf(an.x));
        rt6.y = __builtin_amdgcn_rcpf(0.5f + __expf(an.y));
        rrho.x = __builtin_amdgcn_rcpf(tv[p][0].x);
        rrho.y = __builtin_amdgcn_rcpf(tv[p][0].y);

        const f32x2 jx = splat2(0.5f) * (tv[p][3] + tv[p][6]);
        const f32x2 jy = splat2(0.5f) * (tv[p][3] - tv[p][6]);
        const f32x2 m3 = splat2(0.5f) * (tv[p][4] + tv[p][7]);
        const f32x2 m5 = splat2(0.5f) * (tv[p][4] - tv[p][7]);
        const f32x2 m7 = splat2(0.5f) * (tv[p][5] + tv[p][8]);
        const f32x2 m8 = splat2(0.5f) * (tv[p][5] - tv[p][8]);
        const f32x2 m4 = tv[p][1], m6 = tv[p][2];

        const f32x2 Cs = splat2(1.0f / 0.7f);
        d[p][0] = (m3 - jx * jx * rrho) * Cs;
        d[p][1] = (m4 - jx * jy * rrho) * Cs;
        d[p][2] = (m5 - jy * jy * rrho) * Cs;
        d[p][3] = m6 * rt6;
        d[p][4] = m7 * rt7;
        d[p][5] = m8 * rt8;
    }

    // ---- out[r] = f[r] + sum_c (-Minv[r][3+c]) * d[c]   (Minv cols pre-negated) ----
    #pragma unroll
    for (int r = 0; r < 9; ++r) {
        f32x2 o0 = fv[0][r], o1 = fv[1][r];
        #pragma unroll
        for (int c = 0; c < 6; ++c) {
            const float w = W[672 + r * 6 + c];   // uniform -> s_load (negated Minv)
            o0 = pfmas(w, d[0][c], o0);
            o1 = pfmas(w, d[1][c], o1);
        }
        const float4 vv = make_float4(o0.x, o0.y, o1.x, o1.y);
        *reinterpret_cast<float4*>(out + (size_t)r * n2 + base) = vv;
    }
}

extern "C" void kernel_launch(void* const* d_in, const int* in_sizes, int n_in,
                              void* d_out, int out_size, void* d_ws, size_t ws_size,
                              hipStream_t stream) {
    const float* f    = (const float*)d_in[0];
    const float* j_w1 = (const float*)d_in[1];
    const float* j_b1 = (const float*)d_in[2];
    const float* j_w2 = (const float*)d_in[3];
    const float* j_b2 = (const float*)d_in[4];
    const float* n_w1 = (const float*)d_in[5];
    const float* n_b1 = (const float*)d_in[6];
    const float* n_w2 = (const float*)d_in[7];
    const float* n_b2 = (const float*)d_in[8];
    const float* Mg   = (const float*)d_in[9];
    const float* Minv = (const float*)d_in[10];
    float* out = (float*)d_out;
    float* ws  = (float*)d_ws;

    const int n2 = in_sizes[0] / 9;
    const int pts_per_block = 256 * 4;
    const int grid = (n2 + pts_per_block - 1) / pts_per_block;

    prep_kernel<<<1, 256, 0, stream>>>(j_w1, j_b1, j_w2, j_b2,
                                       n_w1, n_b1, n_w2, n_b2, Mg, Minv, ws);
    mrt_main<<<grid, 256, 0, stream>>>(f, ws, out, n2);
}